// Round 9
// baseline (457.512 us; speedup 1.0000x reference)
//
#include <hip/hip_runtime.h>
#include <math.h>

#define N1CAP 736
#define N2CAP 144
#define S3 132   // padded row-stride for 128-row transposed x tiles

__device__ __forceinline__ float celu1(float x){ return x > 0.f ? x : (expf(x) - 1.f); }
__device__ __forceinline__ float softplus1(float x){ return fmaxf(x, 0.f) + log1pf(expf(-fabsf(x))); }
// valid only for v >= 0 with zero-initialized destination (works on LDS or global pointers)
__device__ __forceinline__ void atomicMaxNonneg(float* p, float v){
    atomicMax((int*)p, __float_as_int(v));
}

// ================= kernel A: per-glimpse stage 1, list-based (no compute atomics) =================
__global__ __launch_bounds__(256) void kA(const float* __restrict__ rgb,
                                          const float* __restrict__ pos,
                                          const int* __restrict__ cl1,
                                          const float* __restrict__ W1l,
                                          const float* __restrict__ b1l,
                                          float* __restrict__ ps1,
                                          float* __restrict__ agg1,
                                          float* __restrict__ cnt1,
                                          int* __restrict__ seg1, int P){
    __shared__ float sp[3*1024];
    __shared__ float srgb[1024];
    __shared__ int   ci[1024];
    __shared__ int   cnt[N1CAP];
    __shared__ int   start[N1CAP+1];
    __shared__ int   cur[N1CAP];
    __shared__ unsigned short pidx[1024];
    __shared__ float wsh[64], bsh[16];
    __shared__ int   red[2];
    __shared__ int   wsum[4];
    const int g = blockIdx.x, tid = threadIdx.x;
    const int base = g * P;
    const bool pfit = (P <= 1024);

    if (tid == 0){ red[0] = 0x7fffffff; red[1] = -1; }
    if (tid < 64) wsh[tid] = W1l[tid];
    if (tid < 16) bsh[tid] = b1l[tid];
    __syncthreads();
    int mn = 0x7fffffff, mx = -1;
    for (int i = tid; i < P; i += 256){
        int c = cl1[base+i];
        if (pfit) ci[i] = c;
        mn = min(mn,c); mx = max(mx,c);
    }
    atomicMin(&red[0], mn); atomicMax(&red[1], mx);
    __syncthreads();
    const int s1 = red[0];
    const int n1 = red[1] - red[0] + 1;
    const bool fast = pfit && (n1 <= N1CAP);

    if (fast){
        for (int t = tid; t < 3*P; t += 256) sp[t] = pos[(size_t)base*3 + t];
        for (int t = tid; t < P;   t += 256) srgb[t] = rgb[base + t];
        for (int l = tid; l < n1;  l += 256) cnt[l] = 0;
        __syncthreads();
        for (int i = tid; i < P; i += 256) atomicAdd(&cnt[ci[i] - s1], 1);
        __syncthreads();
        {
            int b3 = tid*3;
            int a0 = (b3   < n1) ? cnt[b3]   : 0;
            int a1 = (b3+1 < n1) ? cnt[b3+1] : 0;
            int a2 = (b3+2 < n1) ? cnt[b3+2] : 0;
            int s = a0+a1+a2;
            int lane = tid & 63, wv = tid >> 6;
            int ps = s;
            #pragma unroll
            for (int d = 1; d < 64; d <<= 1){
                int t2 = __shfl_up(ps, d, 64);
                if (lane >= d) ps += t2;
            }
            if (lane == 63) wsum[wv] = ps;
            __syncthreads();
            int woff = 0;
            #pragma unroll
            for (int w = 0; w < 4; ++w) woff += (w < wv) ? wsum[w] : 0;
            int excl = woff + ps - s;
            if (b3   < n1){ start[b3]   = excl;       cur[b3]   = excl; }
            if (b3+1 < n1){ start[b3+1] = excl+a0;    cur[b3+1] = excl+a0; }
            if (b3+2 < n1){ start[b3+2] = excl+a0+a1; cur[b3+2] = excl+a0+a1; }
            if (tid == 0) start[n1] = P;
        }
        __syncthreads();
        for (int i = tid; i < P; i += 256){
            int slot = atomicAdd(&cur[ci[i] - s1], 1);
            pidx[slot] = (unsigned short)i;
        }
        __syncthreads();
        for (int l = tid; l < n1; l += 256){
            int s0 = start[l], e0 = start[l+1];
            float sxv=0.f, syv=0.f, szv=0.f;
            for (int k = s0; k < e0; ++k){
                int i = pidx[k];
                sxv += sp[3*i+0]; syv += sp[3*i+1]; szv += sp[3*i+2];
            }
            float ic = 1.0f / (float)max(e0 - s0, 1);
            float mxp = sxv*ic, myp = syv*ic, mzp = szv*ic;
            ps1[(size_t)(s1+l)*3+0] = mxp;
            ps1[(size_t)(s1+l)*3+1] = myp;
            ps1[(size_t)(s1+l)*3+2] = mzp;
            float acc[16];
            #pragma unroll
            for (int j = 0; j < 16; ++j) acc[j] = 0.f;
            for (int k = s0; k < e0; ++k){
                int i = pidx[k];
                float in0 = srgb[i];
                float r0 = sp[3*i+0] - mxp;
                float r1 = sp[3*i+1] - myp;
                float r2 = sp[3*i+2] - mzp;
                #pragma unroll
                for (int j = 0; j < 16; ++j){
                    float v = bsh[j] + in0*wsh[j] + r0*wsh[16+j] + r1*wsh[32+j] + r2*wsh[48+j];
                    acc[j] = fmaxf(acc[j], fmaxf(v, 0.f));
                }
            }
            float4* dst = (float4*)&agg1[(size_t)(s1+l)*16];
            dst[0] = make_float4(acc[0], acc[1], acc[2], acc[3]);
            dst[1] = make_float4(acc[4], acc[5], acc[6], acc[7]);
            dst[2] = make_float4(acc[8], acc[9], acc[10], acc[11]);
            dst[3] = make_float4(acc[12], acc[13], acc[14], acc[15]);
        }
    } else {
        for (int t = tid; t < n1;    t += 256) cnt1[s1+t] = 0.f;
        for (int t = tid; t < n1*3;  t += 256) ps1[(size_t)s1*3+t] = 0.f;
        for (int t = tid; t < n1*16; t += 256) agg1[(size_t)s1*16+t] = 0.f;
        __syncthreads();
        for (int i = tid; i < P; i += 256){
            int idx = base + i; int c = cl1[idx];
            atomicAdd(&ps1[3*c+0], pos[3*idx+0]);
            atomicAdd(&ps1[3*c+1], pos[3*idx+1]);
            atomicAdd(&ps1[3*c+2], pos[3*idx+2]);
            atomicAdd(&cnt1[c], 1.0f);
        }
        __syncthreads();
        for (int l = tid; l < n1; l += 256){
            float ic = 1.0f / fmaxf(cnt1[s1+l], 1.0f);
            ps1[(size_t)(s1+l)*3+0] *= ic; ps1[(size_t)(s1+l)*3+1] *= ic; ps1[(size_t)(s1+l)*3+2] *= ic;
        }
        __syncthreads();
        for (int i = tid; i < P; i += 256){
            int idx = base + i; int c = cl1[idx];
            float in0 = rgb[idx];
            float r0 = pos[3*idx+0] - ps1[3*c+0];
            float r1 = pos[3*idx+1] - ps1[3*c+1];
            float r2 = pos[3*idx+2] - ps1[3*c+2];
            #pragma unroll
            for (int j = 0; j < 16; ++j){
                float v = b1l[j] + in0*W1l[j] + r0*W1l[16+j] + r1*W1l[32+j] + r2*W1l[48+j];
                atomicMaxNonneg(&agg1[(size_t)c*16+j], fmaxf(v, 0.0f));
            }
        }
    }
    if (tid == 0){ seg1[2*g] = s1; seg1[2*g+1] = n1; }
}

// ================= kernel B: per-glimpse stage 2, per-row ILP-4, 4 blocks/CU =================
// round-6 structure (68 VGPR, VALU 71%) with LDS cut to ~39.3 KB for 4 blocks/CU.
__global__ __launch_bounds__(256, 2) void kB(const float* __restrict__ ps1,
                                          const float* __restrict__ agg1,
                                          const int* __restrict__ cl2,
                                          const float* __restrict__ W1g,
                                          const float* __restrict__ b1g,
                                          const float* __restrict__ W2l,
                                          const float* __restrict__ b2l,
                                          const int* __restrict__ seg1,
                                          float* __restrict__ ps2,
                                          float* __restrict__ agg2,
                                          float* __restrict__ cnt2,
                                          int* __restrict__ seg2){
    __shared__ float sx[N2CAP], sy[N2CAP], sz[N2CAP], sc[N2CAP];  // 2.3 KB
    __shared__ float sagg[N2CAP*64];                               // 36.9 KB
    __shared__ int red[2];
    const int g = blockIdx.x, tid = threadIdx.x;
    const int s1 = seg1[2*g], n1 = seg1[2*g+1], e1 = s1 + n1;

    if (tid == 0){ red[0] = 0x7fffffff; red[1] = -1; }
    __syncthreads();
    int mn = 0x7fffffff, mx = -1;
    for (int m = s1 + tid; m < e1; m += 256){ int c = cl2[m]; mn = min(mn,c); mx = max(mx,c); }
    atomicMin(&red[0], mn); atomicMax(&red[1], mx);
    __syncthreads();
    const int s2 = red[0];
    const int n2 = red[1] - red[0] + 1;
    const bool fast = (n2 <= N2CAP);

    if (fast){
        for (int l = tid; l < n2; l += 256){ sx[l]=0.f; sy[l]=0.f; sz[l]=0.f; sc[l]=0.f; }
        for (int t = tid; t < n2*64; t += 256) sagg[t] = 0.f;
        __syncthreads();
        for (int m = s1 + tid; m < e1; m += 256){
            int c = cl2[m] - s2;
            atomicAdd(&sx[c], ps1[3*m+0]);
            atomicAdd(&sy[c], ps1[3*m+1]);
            atomicAdd(&sz[c], ps1[3*m+2]);
            atomicAdd(&sc[c], 1.0f);
        }
        __syncthreads();
        for (int l = tid; l < n2; l += 256){
            float ic = 1.0f / sc[l];
            sx[l] *= ic; sy[l] *= ic; sz[l] *= ic;
        }
        __syncthreads();
        for (int t = tid; t < n2*3; t += 256){
            int l = t/3, d = t - 3*l;
            ps2[(size_t)s2*3 + t] = (d==0) ? sx[l] : ((d==1) ? sy[l] : sz[l]);
        }
        for (int m = s1 + tid; m < e1; m += 256){
            float a[16];
            const float* ar = agg1 + (size_t)m*16;
            #pragma unroll
            for (int k = 0; k < 16; ++k) a[k] = ar[k];
            float in[35];
            // f1 = celu(a @ W1g + b1g): 4 independent accumulator chains
            for (int j = 0; j < 32; j += 4){
                float v0=b1g[j+0], v1=b1g[j+1], v2=b1g[j+2], v3=b1g[j+3];
                #pragma unroll
                for (int k = 0; k < 16; ++k){
                    float x = a[k];
                    const float* w = &W1g[k*32 + j];
                    v0 += x*w[0]; v1 += x*w[1]; v2 += x*w[2]; v3 += x*w[3];
                }
                in[j+0]=celu1(v0); in[j+1]=celu1(v1); in[j+2]=celu1(v2); in[j+3]=celu1(v3);
            }
            int c = cl2[m] - s2;
            in[32] = ps1[3*m+0] - sx[c];
            in[33] = ps1[3*m+1] - sy[c];
            in[34] = ps1[3*m+2] - sz[c];
            float* dst = &sagg[c*64];
            for (int j = 0; j < 64; j += 4){
                float v0=b2l[j+0], v1=b2l[j+1], v2=b2l[j+2], v3=b2l[j+3];
                #pragma unroll
                for (int k = 0; k < 35; ++k){
                    float x = in[k];
                    const float* w = &W2l[k*64 + j];
                    v0 += x*w[0]; v1 += x*w[1]; v2 += x*w[2]; v3 += x*w[3];
                }
                atomicMaxNonneg(&dst[(j+0 + c) & 63], fmaxf(v0, 0.0f));
                atomicMaxNonneg(&dst[(j+1 + c) & 63], fmaxf(v1, 0.0f));
                atomicMaxNonneg(&dst[(j+2 + c) & 63], fmaxf(v2, 0.0f));
                atomicMaxNonneg(&dst[(j+3 + c) & 63], fmaxf(v3, 0.0f));
            }
        }
        __syncthreads();
        for (int t = tid; t < n2*64; t += 256){
            int l = t >> 6, j = t & 63;
            agg2[(size_t)s2*64 + t] = sagg[l*64 + ((j + l) & 63)];
        }
    } else {
        // rare fallback: global atomics into this block's exclusive rows (unroll kept minimal)
        for (int t = tid; t < n2;    t += 256) cnt2[s2+t] = 0.f;
        for (int t = tid; t < n2*3;  t += 256) ps2[(size_t)s2*3+t] = 0.f;
        for (int t = tid; t < n2*64; t += 256) agg2[(size_t)s2*64+t] = 0.f;
        __syncthreads();
        for (int m = s1 + tid; m < e1; m += 256){
            int c = cl2[m];
            atomicAdd(&ps2[3*c+0], ps1[3*m+0]);
            atomicAdd(&ps2[3*c+1], ps1[3*m+1]);
            atomicAdd(&ps2[3*c+2], ps1[3*m+2]);
            atomicAdd(&cnt2[c], 1.0f);
        }
        __syncthreads();
        for (int l = tid; l < n2; l += 256){
            float ic = 1.0f / fmaxf(cnt2[s2+l], 1.0f);
            ps2[(size_t)(s2+l)*3+0] *= ic; ps2[(size_t)(s2+l)*3+1] *= ic; ps2[(size_t)(s2+l)*3+2] *= ic;
        }
        __syncthreads();
        for (int m = s1 + tid; m < e1; m += 256){
            float a[16];
            const float* ar = agg1 + (size_t)m*16;
            #pragma unroll
            for (int k = 0; k < 16; ++k) a[k] = ar[k];
            float in[35];
            #pragma unroll 1
            for (int j = 0; j < 32; ++j){
                float v = b1g[j];
                #pragma unroll 4
                for (int k = 0; k < 16; ++k) v += a[k] * W1g[k*32+j];
                in[j] = celu1(v);
            }
            int c = cl2[m];
            in[32] = ps1[3*m+0] - ps2[3*c+0];
            in[33] = ps1[3*m+1] - ps2[3*c+1];
            in[34] = ps1[3*m+2] - ps2[3*c+2];
            #pragma unroll 1
            for (int j = 0; j < 64; ++j){
                float v = b2l[j];
                #pragma unroll 5
                for (int k = 0; k < 35; ++k) v += in[k] * W2l[k*64+j];
                atomicMaxNonneg(&agg2[(size_t)c*64+j], fmaxf(v, 0.0f));
            }
        }
    }
    if (tid == 0){ seg2[2*g] = s2; seg2[2*g+1] = n2; }
}

// ================= flat GEMM: f2 = celu(agg2[M2x64] @ W2g + b2g) =================
__global__ __launch_bounds__(256) void k_f2f(const float* __restrict__ agg2,
                                             const float* __restrict__ W2g,
                                             const float* __restrict__ b2g,
                                             float* __restrict__ f2, int M2){
    __shared__ float Ws[64*128];   // 32 KB, [k][128]
    __shared__ float xt[32*S3];    // 16.9 KB
    const int tid = threadIdx.x;
    const int m0 = blockIdx.x * 128;
    for (int t = tid; t < 64*128; t += 256) Ws[t] = W2g[t];
    const int tr = tid & 31, tc = tid >> 5;
    float acc[4][16];
    #pragma unroll
    for (int c = 0; c < 16; ++c){
        float b = b2g[tc*16 + c];
        #pragma unroll
        for (int r = 0; r < 4; ++r) acc[r][c] = b;
    }
    for (int c0 = 0; c0 < 64; c0 += 32){
        __syncthreads();
        for (int t = tid; t < 128*8; t += 256){
            int row = t >> 3, kq = t & 7;
            int m = m0 + row;
            float4 v = (m < M2) ? *(const float4*)&agg2[(size_t)m*64 + c0 + kq*4]
                                : make_float4(0.f,0.f,0.f,0.f);
            xt[(kq*4+0)*S3 + row] = v.x;
            xt[(kq*4+1)*S3 + row] = v.y;
            xt[(kq*4+2)*S3 + row] = v.z;
            xt[(kq*4+3)*S3 + row] = v.w;
        }
        __syncthreads();
        #pragma unroll 4
        for (int kk = 0; kk < 32; ++kk){
            int k = c0 + kk;
            float4 xr = *(const float4*)&xt[kk*S3 + tr*4];
            float xv[4] = {xr.x, xr.y, xr.z, xr.w};
            float wv[16];
            #pragma unroll
            for (int q = 0; q < 4; ++q){
                float4 w = *(const float4*)&Ws[k*128 + tc*16 + q*4];
                wv[q*4+0]=w.x; wv[q*4+1]=w.y; wv[q*4+2]=w.z; wv[q*4+3]=w.w;
            }
            #pragma unroll
            for (int r = 0; r < 4; ++r)
                #pragma unroll
                for (int c = 0; c < 16; ++c) acc[r][c] += xv[r]*wv[c];
        }
    }
    #pragma unroll
    for (int r = 0; r < 4; ++r){
        int m = m0 + tr*4 + r;
        if (m < M2){
            #pragma unroll
            for (int q = 0; q < 4; ++q){
                float4 o;
                o.x = celu1(acc[r][q*4+0]); o.y = celu1(acc[r][q*4+1]);
                o.z = celu1(acc[r][q*4+2]); o.w = celu1(acc[r][q*4+3]);
                *(float4*)&f2[(size_t)m*128 + tc*16 + q*4] = o;
            }
        }
    }
}

// ================= stage-3 GEMM + block-local segmax, 4 glimpses/block =================
__global__ __launch_bounds__(256) void k_msg3g(const float* __restrict__ f2,
                                               const float* __restrict__ ps2,
                                               const int* __restrict__ seg2,
                                               const float* __restrict__ W3l,
                                               const float* __restrict__ b3l,
                                               float* __restrict__ agg3, int G){
    __shared__ float Wh[131*64];   // 33.5 KB column half
    __shared__ float xt[32*S3];    // 16.9 KB
    __shared__ float shAgg[256];   // [4 glimpses][64 ch]
    const int tid = threadIdx.x;
    const int cb = blockIdx.y * 64;
    const int g0 = blockIdx.x * 4;
    const int S  = seg2[2*g0];
    int n0 = seg2[2*g0+1];
    int nA = (g0+1 < G) ? seg2[2*(g0+1)+1] : 0;
    int nB = (g0+2 < G) ? seg2[2*(g0+2)+1] : 0;
    int nC = (g0+3 < G) ? seg2[2*(g0+3)+1] : 0;
    const int B1 = n0, B2 = B1 + nA, B3 = B2 + nB, T = B3 + nC;
    for (int t = tid; t < 131*64; t += 256){
        int k = t >> 6, c = t & 63;
        Wh[t] = W3l[k*128 + cb + c];
    }
    shAgg[tid] = 0.f;
    const int tr = tid & 31, tc = tid >> 5;
    float bias[8];
    #pragma unroll
    for (int c = 0; c < 8; ++c) bias[c] = b3l[cb + tc*8 + c];

    for (int w0 = 0; w0 < T; w0 += 128){
        float acc[4][8];
        #pragma unroll
        for (int r = 0; r < 4; ++r)
            #pragma unroll
            for (int c = 0; c < 8; ++c) acc[r][c] = bias[c];
        for (int c0 = 0; c0 < 128; c0 += 32){
            __syncthreads();
            for (int t = tid; t < 128*8; t += 256){
                int row = t >> 3, kq = t & 7;
                int ridx = w0 + row;
                float4 v = (ridx < T) ? *(const float4*)&f2[(size_t)(S+ridx)*128 + c0 + kq*4]
                                      : make_float4(0.f,0.f,0.f,0.f);
                xt[(kq*4+0)*S3 + row] = v.x;
                xt[(kq*4+1)*S3 + row] = v.y;
                xt[(kq*4+2)*S3 + row] = v.z;
                xt[(kq*4+3)*S3 + row] = v.w;
            }
            __syncthreads();
            #pragma unroll 8
            for (int kk = 0; kk < 32; ++kk){
                int k = c0 + kk;
                float4 xr = *(const float4*)&xt[kk*S3 + tr*4];
                float xv[4] = {xr.x, xr.y, xr.z, xr.w};
                float4 wa = *(const float4*)&Wh[k*64 + tc*8];
                float4 wb = *(const float4*)&Wh[k*64 + tc*8 + 4];
                float wv[8] = {wa.x,wa.y,wa.z,wa.w, wb.x,wb.y,wb.z,wb.w};
                #pragma unroll
                for (int r = 0; r < 4; ++r)
                    #pragma unroll
                    for (int c = 0; c < 8; ++c) acc[r][c] += xv[r]*wv[c];
            }
        }
        #pragma unroll
        for (int kk = 0; kk < 3; ++kk){
            const float* w = &Wh[(128+kk)*64 + tc*8];
            float wv[8];
            #pragma unroll
            for (int c = 0; c < 8; ++c) wv[c] = w[c];
            #pragma unroll
            for (int r = 0; r < 4; ++r){
                int ridx = w0 + tr*4 + r;
                float x = (ridx < T) ? ps2[(size_t)(S+ridx)*3 + kk] : 0.f;
                #pragma unroll
                for (int c = 0; c < 8; ++c) acc[r][c] += x*wv[c];
            }
        }
        // run-merged segmax (4 consecutive rows span at most 2 glimpses)
        float mx[8];
        int cur = -1;
        #pragma unroll
        for (int r = 0; r < 4; ++r){
            int ridx = w0 + tr*4 + r;
            if (ridx < T){
                int loc = (ridx >= B1) + (ridx >= B2) + (ridx >= B3);
                if (loc != cur){
                    if (cur >= 0){
                        #pragma unroll
                        for (int c = 0; c < 8; ++c)
                            atomicMaxNonneg(&shAgg[cur*64 + tc*8 + c], mx[c]);
                    }
                    cur = loc;
                    #pragma unroll
                    for (int c = 0; c < 8; ++c) mx[c] = fmaxf(acc[r][c], 0.f);
                } else {
                    #pragma unroll
                    for (int c = 0; c < 8; ++c) mx[c] = fmaxf(mx[c], fmaxf(acc[r][c], 0.f));
                }
            }
        }
        if (cur >= 0){
            #pragma unroll
            for (int c = 0; c < 8; ++c)
                atomicMaxNonneg(&shAgg[cur*64 + tc*8 + c], mx[c]);
        }
    }
    __syncthreads();
    {
        int loc = tid >> 6, c = tid & 63;
        int g = g0 + loc;
        if (g < G)
            agg3[(size_t)g*128 + cb + c] = shAgg[loc*64 + c];
    }
}

// ================= head =================
__global__ __launch_bounds__(256) void k_head(const float* __restrict__ agg3,
                                              const float* __restrict__ W3g,
                                              const float* __restrict__ b3g,
                                              const float* __restrict__ Wlin,
                                              const float* __restrict__ blin,
                                              const float* __restrict__ eps,
                                              float* __restrict__ out, int G){
    __shared__ float a3[128];
    __shared__ float f3s[256];
    __shared__ float hs[256];
    int g = blockIdx.x;
    int j = threadIdx.x;
    if (j < 128) a3[j] = agg3[(size_t)g*128 + j];
    __syncthreads();

    float v = b3g[j];
    for (int k = 0; k < 128; ++k) v += a3[k] * W3g[k*256 + j];
    v = celu1(v);
    f3s[j] = v;
    const size_t o_zm = (size_t)64*G, o_mu = (size_t)128*G, o_sg = (size_t)256*G, o_f3 = (size_t)384*G;
    out[o_f3 + (size_t)g*256 + j] = v;
    __syncthreads();

    float h = blin[j];
    for (int k = 0; k < 256; ++k) h += f3s[k] * Wlin[k*256 + j];
    hs[j] = h;
    __syncthreads();

    if (j < 128){
        float mu = hs[j];
        float sg = softplus1(hs[128 + j]);
        float z = mu + sg * eps[(size_t)g*128 + j];
        out[o_mu + (size_t)g*128 + j] = mu;
        out[o_sg + (size_t)g*128 + j] = sg;
        if (j < 64) out[(size_t)g*64 + j] = z;
        else        out[o_zm + (size_t)g*64 + (j - 64)] = z;
    }
}

extern "C" void kernel_launch(void* const* d_in, const int* in_sizes, int n_in,
                              void* d_out, int out_size, void* d_ws, size_t ws_size,
                              hipStream_t stream) {
    const float* rgb  = (const float*)d_in[0];
    const float* pos  = (const float*)d_in[1];
    const float* W1l  = (const float*)d_in[3];
    const float* b1l  = (const float*)d_in[4];
    const float* W1g  = (const float*)d_in[5];
    const float* b1g  = (const float*)d_in[6];
    const float* W2l  = (const float*)d_in[7];
    const float* b2l  = (const float*)d_in[8];
    const float* W2g  = (const float*)d_in[9];
    const float* b2g  = (const float*)d_in[10];
    const float* W3l  = (const float*)d_in[11];
    const float* b3l  = (const float*)d_in[12];
    const float* W3g  = (const float*)d_in[13];
    const float* b3g  = (const float*)d_in[14];
    const float* Wlin = (const float*)d_in[15];
    const float* blin = (const float*)d_in[16];
    const float* eps  = (const float*)d_in[17];
    const int* cl1 = (const int*)d_in[19];
    const int* cl2 = (const int*)d_in[20];

    const int N  = in_sizes[19];
    const int G  = in_sizes[17] / 128;
    const int M1 = in_sizes[20];
    const int M2 = in_sizes[21];
    const int P  = N / G;

    char* ws = (char*)d_ws;
    auto al = [](size_t x){ return (x + 255) & ~(size_t)255; };
    size_t off = 0;
    float* ps1  = (float*)(ws + off); off = al(off + 12ull*M1);
    size_t uni  = ((size_t)64*M1 > (size_t)512*M2) ? (size_t)64*M1 : (size_t)512*M2;
    float* agg1 = (float*)(ws + off);      // agg1 [M1x16] ... later f2 [M2x128] (disjoint lifetimes)
    float* f2   = (float*)(ws + off);
    off = al(off + uni);
    float* cnt1 = (float*)(ws + off); off = al(off + 4ull*M1);
    float* ps2  = (float*)(ws + off); off = al(off + 12ull*M2);
    float* agg2 = (float*)(ws + off); off = al(off + 256ull*M2);
    float* cnt2 = (float*)(ws + off); off = al(off + 4ull*M2);
    float* agg3 = (float*)(ws + off); off = al(off + 512ull*G);
    int*   seg1 = (int*)  (ws + off); off = al(off + 8ull*G);
    int*   seg2 = (int*)  (ws + off); off = al(off + 8ull*G);
    if (off > ws_size) return;

    kA<<<G, 256, 0, stream>>>(rgb, pos, cl1, W1l, b1l, ps1, agg1, cnt1, seg1, P);
    kB<<<G, 256, 0, stream>>>(ps1, agg1, cl2, W1g, b1g, W2l, b2l, seg1, ps2, agg2, cnt2, seg2);
    int gx = (M2 + 127) / 128;
    k_f2f  <<<gx, 256, 0, stream>>>(agg2, W2g, b2g, f2, M2);
    dim3 g3((G + 3) / 4, 2);
    k_msg3g<<<g3, 256, 0, stream>>>(f2, ps2, seg2, W3l, b3l, agg3, G);
    k_head <<<G, 256, 0, stream>>>(agg3, W3g, b3g, Wlin, blin, eps, (float*)d_out, G);
}

// Round 10
// 403.622 us; speedup vs baseline: 1.1335x; 1.1335x over previous
//
#include <hip/hip_runtime.h>
#include <math.h>

#define N1CAP 736
#define N2CAP 192   // max n2 is in (144,192]; 144 fired the fallback path in round 9
#define S3 132      // padded row-stride for 128-row transposed x tiles

__device__ __forceinline__ float celu1(float x){ return x > 0.f ? x : (expf(x) - 1.f); }
__device__ __forceinline__ float softplus1(float x){ return fmaxf(x, 0.f) + log1pf(expf(-fabsf(x))); }
// valid only for v >= 0 with zero-initialized destination (works on LDS or global pointers)
__device__ __forceinline__ void atomicMaxNonneg(float* p, float v){
    atomicMax((int*)p, __float_as_int(v));
}

// ================= kernel A: per-glimpse stage 1, list-based (no compute atomics) =================
__global__ __launch_bounds__(256) void kA(const float* __restrict__ rgb,
                                          const float* __restrict__ pos,
                                          const int* __restrict__ cl1,
                                          const float* __restrict__ W1l,
                                          const float* __restrict__ b1l,
                                          float* __restrict__ ps1,
                                          float* __restrict__ agg1,
                                          float* __restrict__ cnt1,
                                          int* __restrict__ seg1, int P){
    __shared__ float sp[3*1024];
    __shared__ float srgb[1024];
    __shared__ int   ci[1024];
    __shared__ int   cnt[N1CAP];
    __shared__ int   start[N1CAP+1];
    __shared__ int   cur[N1CAP];
    __shared__ unsigned short pidx[1024];
    __shared__ float wsh[64], bsh[16];
    __shared__ int   red[2];
    __shared__ int   wsum[4];
    const int g = blockIdx.x, tid = threadIdx.x;
    const int base = g * P;
    const bool pfit = (P <= 1024);

    if (tid == 0){ red[0] = 0x7fffffff; red[1] = -1; }
    if (tid < 64) wsh[tid] = W1l[tid];
    if (tid < 16) bsh[tid] = b1l[tid];
    __syncthreads();
    int mn = 0x7fffffff, mx = -1;
    for (int i = tid; i < P; i += 256){
        int c = cl1[base+i];
        if (pfit) ci[i] = c;
        mn = min(mn,c); mx = max(mx,c);
    }
    atomicMin(&red[0], mn); atomicMax(&red[1], mx);
    __syncthreads();
    const int s1 = red[0];
    const int n1 = red[1] - red[0] + 1;
    const bool fast = pfit && (n1 <= N1CAP);

    if (fast){
        for (int t = tid; t < 3*P; t += 256) sp[t] = pos[(size_t)base*3 + t];
        for (int t = tid; t < P;   t += 256) srgb[t] = rgb[base + t];
        for (int l = tid; l < n1;  l += 256) cnt[l] = 0;
        __syncthreads();
        for (int i = tid; i < P; i += 256) atomicAdd(&cnt[ci[i] - s1], 1);
        __syncthreads();
        {
            int b3 = tid*3;
            int a0 = (b3   < n1) ? cnt[b3]   : 0;
            int a1 = (b3+1 < n1) ? cnt[b3+1] : 0;
            int a2 = (b3+2 < n1) ? cnt[b3+2] : 0;
            int s = a0+a1+a2;
            int lane = tid & 63, wv = tid >> 6;
            int ps = s;
            #pragma unroll
            for (int d = 1; d < 64; d <<= 1){
                int t2 = __shfl_up(ps, d, 64);
                if (lane >= d) ps += t2;
            }
            if (lane == 63) wsum[wv] = ps;
            __syncthreads();
            int woff = 0;
            #pragma unroll
            for (int w = 0; w < 4; ++w) woff += (w < wv) ? wsum[w] : 0;
            int excl = woff + ps - s;
            if (b3   < n1){ start[b3]   = excl;       cur[b3]   = excl; }
            if (b3+1 < n1){ start[b3+1] = excl+a0;    cur[b3+1] = excl+a0; }
            if (b3+2 < n1){ start[b3+2] = excl+a0+a1; cur[b3+2] = excl+a0+a1; }
            if (tid == 0) start[n1] = P;
        }
        __syncthreads();
        for (int i = tid; i < P; i += 256){
            int slot = atomicAdd(&cur[ci[i] - s1], 1);
            pidx[slot] = (unsigned short)i;
        }
        __syncthreads();
        for (int l = tid; l < n1; l += 256){
            int s0 = start[l], e0 = start[l+1];
            float sxv=0.f, syv=0.f, szv=0.f;
            for (int k = s0; k < e0; ++k){
                int i = pidx[k];
                sxv += sp[3*i+0]; syv += sp[3*i+1]; szv += sp[3*i+2];
            }
            float ic = 1.0f / (float)max(e0 - s0, 1);
            float mxp = sxv*ic, myp = syv*ic, mzp = szv*ic;
            ps1[(size_t)(s1+l)*3+0] = mxp;
            ps1[(size_t)(s1+l)*3+1] = myp;
            ps1[(size_t)(s1+l)*3+2] = mzp;
            float acc[16];
            #pragma unroll
            for (int j = 0; j < 16; ++j) acc[j] = 0.f;
            for (int k = s0; k < e0; ++k){
                int i = pidx[k];
                float in0 = srgb[i];
                float r0 = sp[3*i+0] - mxp;
                float r1 = sp[3*i+1] - myp;
                float r2 = sp[3*i+2] - mzp;
                #pragma unroll
                for (int j = 0; j < 16; ++j){
                    float v = bsh[j] + in0*wsh[j] + r0*wsh[16+j] + r1*wsh[32+j] + r2*wsh[48+j];
                    acc[j] = fmaxf(acc[j], fmaxf(v, 0.f));
                }
            }
            float4* dst = (float4*)&agg1[(size_t)(s1+l)*16];
            dst[0] = make_float4(acc[0], acc[1], acc[2], acc[3]);
            dst[1] = make_float4(acc[4], acc[5], acc[6], acc[7]);
            dst[2] = make_float4(acc[8], acc[9], acc[10], acc[11]);
            dst[3] = make_float4(acc[12], acc[13], acc[14], acc[15]);
        }
    } else {
        for (int t = tid; t < n1;    t += 256) cnt1[s1+t] = 0.f;
        for (int t = tid; t < n1*3;  t += 256) ps1[(size_t)s1*3+t] = 0.f;
        for (int t = tid; t < n1*16; t += 256) agg1[(size_t)s1*16+t] = 0.f;
        __syncthreads();
        for (int i = tid; i < P; i += 256){
            int idx = base + i; int c = cl1[idx];
            atomicAdd(&ps1[3*c+0], pos[3*idx+0]);
            atomicAdd(&ps1[3*c+1], pos[3*idx+1]);
            atomicAdd(&ps1[3*c+2], pos[3*idx+2]);
            atomicAdd(&cnt1[c], 1.0f);
        }
        __syncthreads();
        for (int l = tid; l < n1; l += 256){
            float ic = 1.0f / fmaxf(cnt1[s1+l], 1.0f);
            ps1[(size_t)(s1+l)*3+0] *= ic; ps1[(size_t)(s1+l)*3+1] *= ic; ps1[(size_t)(s1+l)*3+2] *= ic;
        }
        __syncthreads();
        for (int i = tid; i < P; i += 256){
            int idx = base + i; int c = cl1[idx];
            float in0 = rgb[idx];
            float r0 = pos[3*idx+0] - ps1[3*c+0];
            float r1 = pos[3*idx+1] - ps1[3*c+1];
            float r2 = pos[3*idx+2] - ps1[3*c+2];
            #pragma unroll
            for (int j = 0; j < 16; ++j){
                float v = b1l[j] + in0*W1l[j] + r0*W1l[16+j] + r1*W1l[32+j] + r2*W1l[48+j];
                atomicMaxNonneg(&agg1[(size_t)c*16+j], fmaxf(v, 0.0f));
            }
        }
    }
    if (tid == 0){ seg1[2*g] = s1; seg1[2*g+1] = n1; }
}

// ================= kernel B: per-glimpse stage 2, 2-row x 4-ch ILP =================
// round-6 structure + each thread processes rows m and m+256: weight s_loads amortized
// over 2 rows (8 independent FMA chains per quad). N2CAP=192 (144 fired fallback in r9).
__global__ __launch_bounds__(256) void kB(const float* __restrict__ ps1,
                                          const float* __restrict__ agg1,
                                          const int* __restrict__ cl2,
                                          const float* __restrict__ W1g,
                                          const float* __restrict__ b1g,
                                          const float* __restrict__ W2l,
                                          const float* __restrict__ b2l,
                                          const int* __restrict__ seg1,
                                          float* __restrict__ ps2,
                                          float* __restrict__ agg2,
                                          float* __restrict__ cnt2,
                                          int* __restrict__ seg2){
    __shared__ float sx[N2CAP], sy[N2CAP], sz[N2CAP], sc[N2CAP];
    __shared__ float sagg[N2CAP*64];
    __shared__ int red[2];
    const int g = blockIdx.x, tid = threadIdx.x;
    const int s1 = seg1[2*g], n1 = seg1[2*g+1], e1 = s1 + n1;

    if (tid == 0){ red[0] = 0x7fffffff; red[1] = -1; }
    __syncthreads();
    int mn = 0x7fffffff, mx = -1;
    for (int m = s1 + tid; m < e1; m += 256){ int c = cl2[m]; mn = min(mn,c); mx = max(mx,c); }
    atomicMin(&red[0], mn); atomicMax(&red[1], mx);
    __syncthreads();
    const int s2 = red[0];
    const int n2 = red[1] - red[0] + 1;
    const bool fast = (n2 <= N2CAP);

    if (fast){
        for (int l = tid; l < n2; l += 256){ sx[l]=0.f; sy[l]=0.f; sz[l]=0.f; sc[l]=0.f; }
        for (int t = tid; t < n2*64; t += 256) sagg[t] = 0.f;
        __syncthreads();
        for (int m = s1 + tid; m < e1; m += 256){
            int c = cl2[m] - s2;
            atomicAdd(&sx[c], ps1[3*m+0]);
            atomicAdd(&sy[c], ps1[3*m+1]);
            atomicAdd(&sz[c], ps1[3*m+2]);
            atomicAdd(&sc[c], 1.0f);
        }
        __syncthreads();
        for (int l = tid; l < n2; l += 256){
            float ic = 1.0f / sc[l];
            sx[l] *= ic; sy[l] *= ic; sz[l] *= ic;
        }
        __syncthreads();
        for (int t = tid; t < n2*3; t += 256){
            int l = t/3, d = t - 3*l;
            ps2[(size_t)s2*3 + t] = (d==0) ? sx[l] : ((d==1) ? sy[l] : sz[l]);
        }
        // 2 rows per thread: (m, m+256), stride 512
        for (int m = s1 + tid; m < e1; m += 512){
            const int mB = m + 256;
            const bool hB = (mB < e1);
            float a0[16], a1[16];
            {
                const float4* p = (const float4*)(agg1 + (size_t)m*16);
                float4 q0=p[0], q1=p[1], q2=p[2], q3=p[3];
                a0[0]=q0.x; a0[1]=q0.y; a0[2]=q0.z; a0[3]=q0.w;
                a0[4]=q1.x; a0[5]=q1.y; a0[6]=q1.z; a0[7]=q1.w;
                a0[8]=q2.x; a0[9]=q2.y; a0[10]=q2.z; a0[11]=q2.w;
                a0[12]=q3.x; a0[13]=q3.y; a0[14]=q3.z; a0[15]=q3.w;
            }
            if (hB){
                const float4* p = (const float4*)(agg1 + (size_t)mB*16);
                float4 q0=p[0], q1=p[1], q2=p[2], q3=p[3];
                a1[0]=q0.x; a1[1]=q0.y; a1[2]=q0.z; a1[3]=q0.w;
                a1[4]=q1.x; a1[5]=q1.y; a1[6]=q1.z; a1[7]=q1.w;
                a1[8]=q2.x; a1[9]=q2.y; a1[10]=q2.z; a1[11]=q2.w;
                a1[12]=q3.x; a1[13]=q3.y; a1[14]=q3.z; a1[15]=q3.w;
            } else {
                #pragma unroll
                for (int k = 0; k < 16; ++k) a1[k] = 0.f;
            }
            float in0[35], in1[35];
            for (int j = 0; j < 32; j += 4){
                float v0=b1g[j+0], v1=b1g[j+1], v2=b1g[j+2], v3=b1g[j+3];
                float u0=v0, u1=v1, u2=v2, u3=v3;
                #pragma unroll
                for (int k = 0; k < 16; ++k){
                    const float* w = &W1g[k*32 + j];
                    float w0=w[0], w1=w[1], w2=w[2], w3=w[3];
                    float x0 = a0[k], x1 = a1[k];
                    v0 += x0*w0; v1 += x0*w1; v2 += x0*w2; v3 += x0*w3;
                    u0 += x1*w0; u1 += x1*w1; u2 += x1*w2; u3 += x1*w3;
                }
                in0[j+0]=celu1(v0); in0[j+1]=celu1(v1); in0[j+2]=celu1(v2); in0[j+3]=celu1(v3);
                in1[j+0]=celu1(u0); in1[j+1]=celu1(u1); in1[j+2]=celu1(u2); in1[j+3]=celu1(u3);
            }
            int cA = cl2[m] - s2;
            int cB = hB ? (cl2[mB] - s2) : 0;
            in0[32] = ps1[3*m+0] - sx[cA];
            in0[33] = ps1[3*m+1] - sy[cA];
            in0[34] = ps1[3*m+2] - sz[cA];
            if (hB){
                in1[32] = ps1[3*mB+0] - sx[cB];
                in1[33] = ps1[3*mB+1] - sy[cB];
                in1[34] = ps1[3*mB+2] - sz[cB];
            } else {
                in1[32]=0.f; in1[33]=0.f; in1[34]=0.f;
            }
            float* dA = &sagg[cA*64];
            float* dB = &sagg[cB*64];
            for (int j = 0; j < 64; j += 4){
                float v0=b2l[j+0], v1=b2l[j+1], v2=b2l[j+2], v3=b2l[j+3];
                float u0=v0, u1=v1, u2=v2, u3=v3;
                #pragma unroll
                for (int k = 0; k < 35; ++k){
                    const float* w = &W2l[k*64 + j];
                    float w0=w[0], w1=w[1], w2=w[2], w3=w[3];
                    float x0 = in0[k], x1 = in1[k];
                    v0 += x0*w0; v1 += x0*w1; v2 += x0*w2; v3 += x0*w3;
                    u0 += x1*w0; u1 += x1*w1; u2 += x1*w2; u3 += x1*w3;
                }
                atomicMaxNonneg(&dA[(j+0 + cA) & 63], fmaxf(v0, 0.0f));
                atomicMaxNonneg(&dA[(j+1 + cA) & 63], fmaxf(v1, 0.0f));
                atomicMaxNonneg(&dA[(j+2 + cA) & 63], fmaxf(v2, 0.0f));
                atomicMaxNonneg(&dA[(j+3 + cA) & 63], fmaxf(v3, 0.0f));
                if (hB){
                    atomicMaxNonneg(&dB[(j+0 + cB) & 63], fmaxf(u0, 0.0f));
                    atomicMaxNonneg(&dB[(j+1 + cB) & 63], fmaxf(u1, 0.0f));
                    atomicMaxNonneg(&dB[(j+2 + cB) & 63], fmaxf(u2, 0.0f));
                    atomicMaxNonneg(&dB[(j+3 + cB) & 63], fmaxf(u3, 0.0f));
                }
            }
        }
        __syncthreads();
        for (int t = tid; t < n2*64; t += 256){
            int l = t >> 6, j = t & 63;
            agg2[(size_t)s2*64 + t] = sagg[l*64 + ((j + l) & 63)];
        }
    } else {
        // rare fallback: global atomics into this block's exclusive rows
        for (int t = tid; t < n2;    t += 256) cnt2[s2+t] = 0.f;
        for (int t = tid; t < n2*3;  t += 256) ps2[(size_t)s2*3+t] = 0.f;
        for (int t = tid; t < n2*64; t += 256) agg2[(size_t)s2*64+t] = 0.f;
        __syncthreads();
        for (int m = s1 + tid; m < e1; m += 256){
            int c = cl2[m];
            atomicAdd(&ps2[3*c+0], ps1[3*m+0]);
            atomicAdd(&ps2[3*c+1], ps1[3*m+1]);
            atomicAdd(&ps2[3*c+2], ps1[3*m+2]);
            atomicAdd(&cnt2[c], 1.0f);
        }
        __syncthreads();
        for (int l = tid; l < n2; l += 256){
            float ic = 1.0f / fmaxf(cnt2[s2+l], 1.0f);
            ps2[(size_t)(s2+l)*3+0] *= ic; ps2[(size_t)(s2+l)*3+1] *= ic; ps2[(size_t)(s2+l)*3+2] *= ic;
        }
        __syncthreads();
        for (int m = s1 + tid; m < e1; m += 256){
            float a[16];
            const float* ar = agg1 + (size_t)m*16;
            #pragma unroll
            for (int k = 0; k < 16; ++k) a[k] = ar[k];
            float in[35];
            #pragma unroll 1
            for (int j = 0; j < 32; ++j){
                float v = b1g[j];
                #pragma unroll 4
                for (int k = 0; k < 16; ++k) v += a[k] * W1g[k*32+j];
                in[j] = celu1(v);
            }
            int c = cl2[m];
            in[32] = ps1[3*m+0] - ps2[3*c+0];
            in[33] = ps1[3*m+1] - ps2[3*c+1];
            in[34] = ps1[3*m+2] - ps2[3*c+2];
            #pragma unroll 1
            for (int j = 0; j < 64; ++j){
                float v = b2l[j];
                #pragma unroll 5
                for (int k = 0; k < 35; ++k) v += in[k] * W2l[k*64+j];
                atomicMaxNonneg(&agg2[(size_t)c*64+j], fmaxf(v, 0.0f));
            }
        }
    }
    if (tid == 0){ seg2[2*g] = s2; seg2[2*g+1] = n2; }
}

// ================= flat GEMM: f2 = celu(agg2[M2x64] @ W2g + b2g) =================
__global__ __launch_bounds__(256) void k_f2f(const float* __restrict__ agg2,
                                             const float* __restrict__ W2g,
                                             const float* __restrict__ b2g,
                                             float* __restrict__ f2, int M2){
    __shared__ float Ws[64*128];   // 32 KB, [k][128]
    __shared__ float xt[32*S3];    // 16.9 KB
    const int tid = threadIdx.x;
    const int m0 = blockIdx.x * 128;
    for (int t = tid; t < 64*128; t += 256) Ws[t] = W2g[t];
    const int tr = tid & 31, tc = tid >> 5;
    float acc[4][16];
    #pragma unroll
    for (int c = 0; c < 16; ++c){
        float b = b2g[tc*16 + c];
        #pragma unroll
        for (int r = 0; r < 4; ++r) acc[r][c] = b;
    }
    for (int c0 = 0; c0 < 64; c0 += 32){
        __syncthreads();
        for (int t = tid; t < 128*8; t += 256){
            int row = t >> 3, kq = t & 7;
            int m = m0 + row;
            float4 v = (m < M2) ? *(const float4*)&agg2[(size_t)m*64 + c0 + kq*4]
                                : make_float4(0.f,0.f,0.f,0.f);
            xt[(kq*4+0)*S3 + row] = v.x;
            xt[(kq*4+1)*S3 + row] = v.y;
            xt[(kq*4+2)*S3 + row] = v.z;
            xt[(kq*4+3)*S3 + row] = v.w;
        }
        __syncthreads();
        #pragma unroll 4
        for (int kk = 0; kk < 32; ++kk){
            int k = c0 + kk;
            float4 xr = *(const float4*)&xt[kk*S3 + tr*4];
            float xv[4] = {xr.x, xr.y, xr.z, xr.w};
            float wv[16];
            #pragma unroll
            for (int q = 0; q < 4; ++q){
                float4 w = *(const float4*)&Ws[k*128 + tc*16 + q*4];
                wv[q*4+0]=w.x; wv[q*4+1]=w.y; wv[q*4+2]=w.z; wv[q*4+3]=w.w;
            }
            #pragma unroll
            for (int r = 0; r < 4; ++r)
                #pragma unroll
                for (int c = 0; c < 16; ++c) acc[r][c] += xv[r]*wv[c];
        }
    }
    #pragma unroll
    for (int r = 0; r < 4; ++r){
        int m = m0 + tr*4 + r;
        if (m < M2){
            #pragma unroll
            for (int q = 0; q < 4; ++q){
                float4 o;
                o.x = celu1(acc[r][q*4+0]); o.y = celu1(acc[r][q*4+1]);
                o.z = celu1(acc[r][q*4+2]); o.w = celu1(acc[r][q*4+3]);
                *(float4*)&f2[(size_t)m*128 + tc*16 + q*4] = o;
            }
        }
    }
}

// ================= stage-3 GEMM + block-local segmax, 4 glimpses/block =================
__global__ __launch_bounds__(256) void k_msg3g(const float* __restrict__ f2,
                                               const float* __restrict__ ps2,
                                               const int* __restrict__ seg2,
                                               const float* __restrict__ W3l,
                                               const float* __restrict__ b3l,
                                               float* __restrict__ agg3, int G){
    __shared__ float Wh[131*64];   // 33.5 KB column half
    __shared__ float xt[32*S3];    // 16.9 KB
    __shared__ float shAgg[256];   // [4 glimpses][64 ch]
    const int tid = threadIdx.x;
    const int cb = blockIdx.y * 64;
    const int g0 = blockIdx.x * 4;
    const int S  = seg2[2*g0];
    int n0 = seg2[2*g0+1];
    int nA = (g0+1 < G) ? seg2[2*(g0+1)+1] : 0;
    int nB = (g0+2 < G) ? seg2[2*(g0+2)+1] : 0;
    int nC = (g0+3 < G) ? seg2[2*(g0+3)+1] : 0;
    const int B1 = n0, B2 = B1 + nA, B3 = B2 + nB, T = B3 + nC;
    for (int t = tid; t < 131*64; t += 256){
        int k = t >> 6, c = t & 63;
        Wh[t] = W3l[k*128 + cb + c];
    }
    shAgg[tid] = 0.f;
    const int tr = tid & 31, tc = tid >> 5;
    float bias[8];
    #pragma unroll
    for (int c = 0; c < 8; ++c) bias[c] = b3l[cb + tc*8 + c];

    for (int w0 = 0; w0 < T; w0 += 128){
        float acc[4][8];
        #pragma unroll
        for (int r = 0; r < 4; ++r)
            #pragma unroll
            for (int c = 0; c < 8; ++c) acc[r][c] = bias[c];
        for (int c0 = 0; c0 < 128; c0 += 32){
            __syncthreads();
            for (int t = tid; t < 128*8; t += 256){
                int row = t >> 3, kq = t & 7;
                int ridx = w0 + row;
                float4 v = (ridx < T) ? *(const float4*)&f2[(size_t)(S+ridx)*128 + c0 + kq*4]
                                      : make_float4(0.f,0.f,0.f,0.f);
                xt[(kq*4+0)*S3 + row] = v.x;
                xt[(kq*4+1)*S3 + row] = v.y;
                xt[(kq*4+2)*S3 + row] = v.z;
                xt[(kq*4+3)*S3 + row] = v.w;
            }
            __syncthreads();
            #pragma unroll 8
            for (int kk = 0; kk < 32; ++kk){
                int k = c0 + kk;
                float4 xr = *(const float4*)&xt[kk*S3 + tr*4];
                float xv[4] = {xr.x, xr.y, xr.z, xr.w};
                float4 wa = *(const float4*)&Wh[k*64 + tc*8];
                float4 wb = *(const float4*)&Wh[k*64 + tc*8 + 4];
                float wv[8] = {wa.x,wa.y,wa.z,wa.w, wb.x,wb.y,wb.z,wb.w};
                #pragma unroll
                for (int r = 0; r < 4; ++r)
                    #pragma unroll
                    for (int c = 0; c < 8; ++c) acc[r][c] += xv[r]*wv[c];
            }
        }
        #pragma unroll
        for (int kk = 0; kk < 3; ++kk){
            const float* w = &Wh[(128+kk)*64 + tc*8];
            float wv[8];
            #pragma unroll
            for (int c = 0; c < 8; ++c) wv[c] = w[c];
            #pragma unroll
            for (int r = 0; r < 4; ++r){
                int ridx = w0 + tr*4 + r;
                float x = (ridx < T) ? ps2[(size_t)(S+ridx)*3 + kk] : 0.f;
                #pragma unroll
                for (int c = 0; c < 8; ++c) acc[r][c] += x*wv[c];
            }
        }
        // run-merged segmax (4 consecutive rows span at most 2 glimpses)
        float mx[8];
        int cur = -1;
        #pragma unroll
        for (int r = 0; r < 4; ++r){
            int ridx = w0 + tr*4 + r;
            if (ridx < T){
                int loc = (ridx >= B1) + (ridx >= B2) + (ridx >= B3);
                if (loc != cur){
                    if (cur >= 0){
                        #pragma unroll
                        for (int c = 0; c < 8; ++c)
                            atomicMaxNonneg(&shAgg[cur*64 + tc*8 + c], mx[c]);
                    }
                    cur = loc;
                    #pragma unroll
                    for (int c = 0; c < 8; ++c) mx[c] = fmaxf(acc[r][c], 0.f);
                } else {
                    #pragma unroll
                    for (int c = 0; c < 8; ++c) mx[c] = fmaxf(mx[c], fmaxf(acc[r][c], 0.f));
                }
            }
        }
        if (cur >= 0){
            #pragma unroll
            for (int c = 0; c < 8; ++c)
                atomicMaxNonneg(&shAgg[cur*64 + tc*8 + c], mx[c]);
        }
    }
    __syncthreads();
    {
        int loc = tid >> 6, c = tid & 63;
        int g = g0 + loc;
        if (g < G)
            agg3[(size_t)g*128 + cb + c] = shAgg[loc*64 + c];
    }
}

// ================= head =================
__global__ __launch_bounds__(256) void k_head(const float* __restrict__ agg3,
                                              const float* __restrict__ W3g,
                                              const float* __restrict__ b3g,
                                              const float* __restrict__ Wlin,
                                              const float* __restrict__ blin,
                                              const float* __restrict__ eps,
                                              float* __restrict__ out, int G){
    __shared__ float a3[128];
    __shared__ float f3s[256];
    __shared__ float hs[256];
    int g = blockIdx.x;
    int j = threadIdx.x;
    if (j < 128) a3[j] = agg3[(size_t)g*128 + j];
    __syncthreads();

    float v = b3g[j];
    for (int k = 0; k < 128; ++k) v += a3[k] * W3g[k*256 + j];
    v = celu1(v);
    f3s[j] = v;
    const size_t o_zm = (size_t)64*G, o_mu = (size_t)128*G, o_sg = (size_t)256*G, o_f3 = (size_t)384*G;
    out[o_f3 + (size_t)g*256 + j] = v;
    __syncthreads();

    float h = blin[j];
    for (int k = 0; k < 256; ++k) h += f3s[k] * Wlin[k*256 + j];
    hs[j] = h;
    __syncthreads();

    if (j < 128){
        float mu = hs[j];
        float sg = softplus1(hs[128 + j]);
        float z = mu + sg * eps[(size_t)g*128 + j];
        out[o_mu + (size_t)g*128 + j] = mu;
        out[o_sg + (size_t)g*128 + j] = sg;
        if (j < 64) out[(size_t)g*64 + j] = z;
        else        out[o_zm + (size_t)g*64 + (j - 64)] = z;
    }
}

extern "C" void kernel_launch(void* const* d_in, const int* in_sizes, int n_in,
                              void* d_out, int out_size, void* d_ws, size_t ws_size,
                              hipStream_t stream) {
    const float* rgb  = (const float*)d_in[0];
    const float* pos  = (const float*)d_in[1];
    const float* W1l  = (const float*)d_in[3];
    const float* b1l  = (const float*)d_in[4];
    const float* W1g  = (const float*)d_in[5];
    const float* b1g  = (const float*)d_in[6];
    const float* W2l  = (const float*)d_in[7];
    const float* b2l  = (const float*)d_in[8];
    const float* W2g  = (const float*)d_in[9];
    const float* b2g  = (const float*)d_in[10];
    const float* W3l  = (const float*)d_in[11];
    const float* b3l  = (const float*)d_in[12];
    const float* W3g  = (const float*)d_in[13];
    const float* b3g  = (const float*)d_in[14];
    const float* Wlin = (const float*)d_in[15];
    const float* blin = (const float*)d_in[16];
    const float* eps  = (const float*)d_in[17];
    const int* cl1 = (const int*)d_in[19];
    const int* cl2 = (const int*)d_in[20];

    const int N  = in_sizes[19];
    const int G  = in_sizes[17] / 128;
    const int M1 = in_sizes[20];
    const int M2 = in_sizes[21];
    const int P  = N / G;

    char* ws = (char*)d_ws;
    auto al = [](size_t x){ return (x + 255) & ~(size_t)255; };
    size_t off = 0;
    float* ps1  = (float*)(ws + off); off = al(off + 12ull*M1);
    size_t uni  = ((size_t)64*M1 > (size_t)512*M2) ? (size_t)64*M1 : (size_t)512*M2;
    float* agg1 = (float*)(ws + off);      // agg1 [M1x16] ... later f2 [M2x128] (disjoint lifetimes)
    float* f2   = (float*)(ws + off);
    off = al(off + uni);
    float* cnt1 = (float*)(ws + off); off = al(off + 4ull*M1);
    float* ps2  = (float*)(ws + off); off = al(off + 12ull*M2);
    float* agg2 = (float*)(ws + off); off = al(off + 256ull*M2);
    float* cnt2 = (float*)(ws + off); off = al(off + 4ull*M2);
    float* agg3 = (float*)(ws + off); off = al(off + 512ull*G);
    int*   seg1 = (int*)  (ws + off); off = al(off + 8ull*G);
    int*   seg2 = (int*)  (ws + off); off = al(off + 8ull*G);
    if (off > ws_size) return;

    kA<<<G, 256, 0, stream>>>(rgb, pos, cl1, W1l, b1l, ps1, agg1, cnt1, seg1, P);
    kB<<<G, 256, 0, stream>>>(ps1, agg1, cl2, W1g, b1g, W2l, b2l, seg1, ps2, agg2, cnt2, seg2);
    int gx = (M2 + 127) / 128;
    k_f2f  <<<gx, 256, 0, stream>>>(agg2, W2g, b2g, f2, M2);
    dim3 g3((G + 3) / 4, 2);
    k_msg3g<<<g3, 256, 0, stream>>>(f2, ps2, seg2, W3l, b3l, agg3, G);
    k_head <<<G, 256, 0, stream>>>(agg3, W3g, b3g, Wlin, blin, eps, (float*)d_out, G);
}

// Round 11
// 381.111 us; speedup vs baseline: 1.2005x; 1.0591x over previous
//
#include <hip/hip_runtime.h>
#include <math.h>

#define N1CAP 736
#define N2CAP 192   // max n2 is in (144,192]; 144 fired the fallback path in round 9
#define S3 132      // padded row-stride for 128-row transposed x tiles

// fast celu: v_exp_f32 path (~1 ulp), only used for x<0; threshold 7.8e-2 >> error
__device__ __forceinline__ float celu1(float x){ return x > 0.f ? x : (__expf(x) - 1.f); }
__device__ __forceinline__ float softplus1(float x){ return fmaxf(x, 0.f) + log1pf(__expf(-fabsf(x))); }
// valid only for v >= 0 with zero-initialized destination (works on LDS or global pointers)
__device__ __forceinline__ void atomicMaxNonneg(float* p, float v){
    atomicMax((int*)p, __float_as_int(v));
}

// ================= kernel A: per-glimpse stage 1, list-based (no compute atomics) =================
__global__ __launch_bounds__(256) void kA(const float* __restrict__ rgb,
                                          const float* __restrict__ pos,
                                          const int* __restrict__ cl1,
                                          const float* __restrict__ W1l,
                                          const float* __restrict__ b1l,
                                          float* __restrict__ ps1,
                                          float* __restrict__ agg1,
                                          float* __restrict__ cnt1,
                                          int* __restrict__ seg1, int P){
    __shared__ float sp[3*1024];
    __shared__ float srgb[1024];
    __shared__ int   ci[1024];
    __shared__ int   cnt[N1CAP];
    __shared__ int   start[N1CAP+1];
    __shared__ int   cur[N1CAP];
    __shared__ unsigned short pidx[1024];
    __shared__ float wsh[64], bsh[16];
    __shared__ int   red[2];
    __shared__ int   wsum[4];
    const int g = blockIdx.x, tid = threadIdx.x;
    const int base = g * P;
    const bool pfit = (P <= 1024);

    if (tid == 0){ red[0] = 0x7fffffff; red[1] = -1; }
    if (tid < 64) wsh[tid] = W1l[tid];
    if (tid < 16) bsh[tid] = b1l[tid];
    __syncthreads();
    int mn = 0x7fffffff, mx = -1;
    for (int i = tid; i < P; i += 256){
        int c = cl1[base+i];
        if (pfit) ci[i] = c;
        mn = min(mn,c); mx = max(mx,c);
    }
    atomicMin(&red[0], mn); atomicMax(&red[1], mx);
    __syncthreads();
    const int s1 = red[0];
    const int n1 = red[1] - red[0] + 1;
    const bool fast = pfit && (n1 <= N1CAP);

    if (fast){
        for (int t = tid; t < 3*P; t += 256) sp[t] = pos[(size_t)base*3 + t];
        for (int t = tid; t < P;   t += 256) srgb[t] = rgb[base + t];
        for (int l = tid; l < n1;  l += 256) cnt[l] = 0;
        __syncthreads();
        for (int i = tid; i < P; i += 256) atomicAdd(&cnt[ci[i] - s1], 1);
        __syncthreads();
        {
            int b3 = tid*3;
            int a0 = (b3   < n1) ? cnt[b3]   : 0;
            int a1 = (b3+1 < n1) ? cnt[b3+1] : 0;
            int a2 = (b3+2 < n1) ? cnt[b3+2] : 0;
            int s = a0+a1+a2;
            int lane = tid & 63, wv = tid >> 6;
            int ps = s;
            #pragma unroll
            for (int d = 1; d < 64; d <<= 1){
                int t2 = __shfl_up(ps, d, 64);
                if (lane >= d) ps += t2;
            }
            if (lane == 63) wsum[wv] = ps;
            __syncthreads();
            int woff = 0;
            #pragma unroll
            for (int w = 0; w < 4; ++w) woff += (w < wv) ? wsum[w] : 0;
            int excl = woff + ps - s;
            if (b3   < n1){ start[b3]   = excl;       cur[b3]   = excl; }
            if (b3+1 < n1){ start[b3+1] = excl+a0;    cur[b3+1] = excl+a0; }
            if (b3+2 < n1){ start[b3+2] = excl+a0+a1; cur[b3+2] = excl+a0+a1; }
            if (tid == 0) start[n1] = P;
        }
        __syncthreads();
        for (int i = tid; i < P; i += 256){
            int slot = atomicAdd(&cur[ci[i] - s1], 1);
            pidx[slot] = (unsigned short)i;
        }
        __syncthreads();
        for (int l = tid; l < n1; l += 256){
            int s0 = start[l], e0 = start[l+1];
            float sxv=0.f, syv=0.f, szv=0.f;
            for (int k = s0; k < e0; ++k){
                int i = pidx[k];
                sxv += sp[3*i+0]; syv += sp[3*i+1]; szv += sp[3*i+2];
            }
            float ic = 1.0f / (float)max(e0 - s0, 1);
            float mxp = sxv*ic, myp = syv*ic, mzp = szv*ic;
            ps1[(size_t)(s1+l)*3+0] = mxp;
            ps1[(size_t)(s1+l)*3+1] = myp;
            ps1[(size_t)(s1+l)*3+2] = mzp;
            float acc[16];
            #pragma unroll
            for (int j = 0; j < 16; ++j) acc[j] = 0.f;
            for (int k = s0; k < e0; ++k){
                int i = pidx[k];
                float in0 = srgb[i];
                float r0 = sp[3*i+0] - mxp;
                float r1 = sp[3*i+1] - myp;
                float r2 = sp[3*i+2] - mzp;
                #pragma unroll
                for (int j = 0; j < 16; ++j){
                    float v = bsh[j] + in0*wsh[j] + r0*wsh[16+j] + r1*wsh[32+j] + r2*wsh[48+j];
                    acc[j] = fmaxf(acc[j], fmaxf(v, 0.f));
                }
            }
            float4* dst = (float4*)&agg1[(size_t)(s1+l)*16];
            dst[0] = make_float4(acc[0], acc[1], acc[2], acc[3]);
            dst[1] = make_float4(acc[4], acc[5], acc[6], acc[7]);
            dst[2] = make_float4(acc[8], acc[9], acc[10], acc[11]);
            dst[3] = make_float4(acc[12], acc[13], acc[14], acc[15]);
        }
    } else {
        for (int t = tid; t < n1;    t += 256) cnt1[s1+t] = 0.f;
        for (int t = tid; t < n1*3;  t += 256) ps1[(size_t)s1*3+t] = 0.f;
        for (int t = tid; t < n1*16; t += 256) agg1[(size_t)s1*16+t] = 0.f;
        __syncthreads();
        for (int i = tid; i < P; i += 256){
            int idx = base + i; int c = cl1[idx];
            atomicAdd(&ps1[3*c+0], pos[3*idx+0]);
            atomicAdd(&ps1[3*c+1], pos[3*idx+1]);
            atomicAdd(&ps1[3*c+2], pos[3*idx+2]);
            atomicAdd(&cnt1[c], 1.0f);
        }
        __syncthreads();
        for (int l = tid; l < n1; l += 256){
            float ic = 1.0f / fmaxf(cnt1[s1+l], 1.0f);
            ps1[(size_t)(s1+l)*3+0] *= ic; ps1[(size_t)(s1+l)*3+1] *= ic; ps1[(size_t)(s1+l)*3+2] *= ic;
        }
        __syncthreads();
        for (int i = tid; i < P; i += 256){
            int idx = base + i; int c = cl1[idx];
            float in0 = rgb[idx];
            float r0 = pos[3*idx+0] - ps1[3*c+0];
            float r1 = pos[3*idx+1] - ps1[3*c+1];
            float r2 = pos[3*idx+2] - ps1[3*c+2];
            #pragma unroll
            for (int j = 0; j < 16; ++j){
                float v = b1l[j] + in0*W1l[j] + r0*W1l[16+j] + r1*W1l[32+j] + r2*W1l[48+j];
                atomicMaxNonneg(&agg1[(size_t)c*16+j], fmaxf(v, 0.0f));
            }
        }
    }
    if (tid == 0){ seg1[2*g] = s1; seg1[2*g+1] = n1; }
}

// ================= kernel B: per-glimpse stage 2, per-row 4-way ILP (round-6 config) =================
__global__ __launch_bounds__(256) void kB(const float* __restrict__ ps1,
                                          const float* __restrict__ agg1,
                                          const int* __restrict__ cl2,
                                          const float* __restrict__ W1g,
                                          const float* __restrict__ b1g,
                                          const float* __restrict__ W2l,
                                          const float* __restrict__ b2l,
                                          const int* __restrict__ seg1,
                                          float* __restrict__ ps2,
                                          float* __restrict__ agg2,
                                          float* __restrict__ cnt2,
                                          int* __restrict__ seg2){
    __shared__ float sx[N2CAP], sy[N2CAP], sz[N2CAP], sc[N2CAP];
    __shared__ float sagg[N2CAP*64];
    __shared__ int red[2];
    const int g = blockIdx.x, tid = threadIdx.x;
    const int s1 = seg1[2*g], n1 = seg1[2*g+1], e1 = s1 + n1;

    if (tid == 0){ red[0] = 0x7fffffff; red[1] = -1; }
    __syncthreads();
    int mn = 0x7fffffff, mx = -1;
    for (int m = s1 + tid; m < e1; m += 256){ int c = cl2[m]; mn = min(mn,c); mx = max(mx,c); }
    atomicMin(&red[0], mn); atomicMax(&red[1], mx);
    __syncthreads();
    const int s2 = red[0];
    const int n2 = red[1] - red[0] + 1;
    const bool fast = (n2 <= N2CAP);

    if (fast){
        for (int l = tid; l < n2; l += 256){ sx[l]=0.f; sy[l]=0.f; sz[l]=0.f; sc[l]=0.f; }
        for (int t = tid; t < n2*64; t += 256) sagg[t] = 0.f;
        __syncthreads();
        for (int m = s1 + tid; m < e1; m += 256){
            int c = cl2[m] - s2;
            atomicAdd(&sx[c], ps1[3*m+0]);
            atomicAdd(&sy[c], ps1[3*m+1]);
            atomicAdd(&sz[c], ps1[3*m+2]);
            atomicAdd(&sc[c], 1.0f);
        }
        __syncthreads();
        for (int l = tid; l < n2; l += 256){
            float ic = 1.0f / sc[l];
            sx[l] *= ic; sy[l] *= ic; sz[l] *= ic;
        }
        __syncthreads();
        for (int t = tid; t < n2*3; t += 256){
            int l = t/3, d = t - 3*l;
            ps2[(size_t)s2*3 + t] = (d==0) ? sx[l] : ((d==1) ? sy[l] : sz[l]);
        }
        for (int m = s1 + tid; m < e1; m += 256){
            float a[16];
            const float* ar = agg1 + (size_t)m*16;
            #pragma unroll
            for (int k = 0; k < 16; ++k) a[k] = ar[k];
            float in[35];
            // f1 = celu(a @ W1g + b1g): 4 independent accumulator chains
            for (int j = 0; j < 32; j += 4){
                float v0=b1g[j+0], v1=b1g[j+1], v2=b1g[j+2], v3=b1g[j+3];
                #pragma unroll
                for (int k = 0; k < 16; ++k){
                    float x = a[k];
                    const float* w = &W1g[k*32 + j];
                    v0 += x*w[0]; v1 += x*w[1]; v2 += x*w[2]; v3 += x*w[3];
                }
                in[j+0]=celu1(v0); in[j+1]=celu1(v1); in[j+2]=celu1(v2); in[j+3]=celu1(v3);
            }
            int c = cl2[m] - s2;
            in[32] = ps1[3*m+0] - sx[c];
            in[33] = ps1[3*m+1] - sy[c];
            in[34] = ps1[3*m+2] - sz[c];
            float* dst = &sagg[c*64];
            for (int j = 0; j < 64; j += 4){
                float v0=b2l[j+0], v1=b2l[j+1], v2=b2l[j+2], v3=b2l[j+3];
                #pragma unroll
                for (int k = 0; k < 35; ++k){
                    float x = in[k];
                    const float* w = &W2l[k*64 + j];
                    v0 += x*w[0]; v1 += x*w[1]; v2 += x*w[2]; v3 += x*w[3];
                }
                atomicMaxNonneg(&dst[(j+0 + c) & 63], fmaxf(v0, 0.0f));
                atomicMaxNonneg(&dst[(j+1 + c) & 63], fmaxf(v1, 0.0f));
                atomicMaxNonneg(&dst[(j+2 + c) & 63], fmaxf(v2, 0.0f));
                atomicMaxNonneg(&dst[(j+3 + c) & 63], fmaxf(v3, 0.0f));
            }
        }
        __syncthreads();
        for (int t = tid; t < n2*64; t += 256){
            int l = t >> 6, j = t & 63;
            agg2[(size_t)s2*64 + t] = sagg[l*64 + ((j + l) & 63)];
        }
    } else {
        // rare fallback: global atomics into this block's exclusive rows
        for (int t = tid; t < n2;    t += 256) cnt2[s2+t] = 0.f;
        for (int t = tid; t < n2*3;  t += 256) ps2[(size_t)s2*3+t] = 0.f;
        for (int t = tid; t < n2*64; t += 256) agg2[(size_t)s2*64+t] = 0.f;
        __syncthreads();
        for (int m = s1 + tid; m < e1; m += 256){
            int c = cl2[m];
            atomicAdd(&ps2[3*c+0], ps1[3*m+0]);
            atomicAdd(&ps2[3*c+1], ps1[3*m+1]);
            atomicAdd(&ps2[3*c+2], ps1[3*m+2]);
            atomicAdd(&cnt2[c], 1.0f);
        }
        __syncthreads();
        for (int l = tid; l < n2; l += 256){
            float ic = 1.0f / fmaxf(cnt2[s2+l], 1.0f);
            ps2[(size_t)(s2+l)*3+0] *= ic; ps2[(size_t)(s2+l)*3+1] *= ic; ps2[(size_t)(s2+l)*3+2] *= ic;
        }
        __syncthreads();
        for (int m = s1 + tid; m < e1; m += 256){
            float a[16];
            const float* ar = agg1 + (size_t)m*16;
            #pragma unroll
            for (int k = 0; k < 16; ++k) a[k] = ar[k];
            float in[35];
            #pragma unroll 1
            for (int j = 0; j < 32; ++j){
                float v = b1g[j];
                #pragma unroll 4
                for (int k = 0; k < 16; ++k) v += a[k] * W1g[k*32+j];
                in[j] = celu1(v);
            }
            int c = cl2[m];
            in[32] = ps1[3*m+0] - ps2[3*c+0];
            in[33] = ps1[3*m+1] - ps2[3*c+1];
            in[34] = ps1[3*m+2] - ps2[3*c+2];
            #pragma unroll 1
            for (int j = 0; j < 64; ++j){
                float v = b2l[j];
                #pragma unroll 5
                for (int k = 0; k < 35; ++k) v += in[k] * W2l[k*64+j];
                atomicMaxNonneg(&agg2[(size_t)c*64+j], fmaxf(v, 0.0f));
            }
        }
    }
    if (tid == 0){ seg2[2*g] = s2; seg2[2*g+1] = n2; }
}

// ================= flat GEMM: f2 = celu(agg2[M2x64] @ W2g + b2g) =================
__global__ __launch_bounds__(256) void k_f2f(const float* __restrict__ agg2,
                                             const float* __restrict__ W2g,
                                             const float* __restrict__ b2g,
                                             float* __restrict__ f2, int M2){
    __shared__ float Ws[64*128];   // 32 KB, [k][128]
    __shared__ float xt[32*S3];    // 16.9 KB
    const int tid = threadIdx.x;
    const int m0 = blockIdx.x * 128;
    for (int t = tid; t < 64*128; t += 256) Ws[t] = W2g[t];
    const int tr = tid & 31, tc = tid >> 5;
    float acc[4][16];
    #pragma unroll
    for (int c = 0; c < 16; ++c){
        float b = b2g[tc*16 + c];
        #pragma unroll
        for (int r = 0; r < 4; ++r) acc[r][c] = b;
    }
    for (int c0 = 0; c0 < 64; c0 += 32){
        __syncthreads();
        for (int t = tid; t < 128*8; t += 256){
            int row = t >> 3, kq = t & 7;
            int m = m0 + row;
            float4 v = (m < M2) ? *(const float4*)&agg2[(size_t)m*64 + c0 + kq*4]
                                : make_float4(0.f,0.f,0.f,0.f);
            xt[(kq*4+0)*S3 + row] = v.x;
            xt[(kq*4+1)*S3 + row] = v.y;
            xt[(kq*4+2)*S3 + row] = v.z;
            xt[(kq*4+3)*S3 + row] = v.w;
        }
        __syncthreads();
        #pragma unroll 4
        for (int kk = 0; kk < 32; ++kk){
            int k = c0 + kk;
            float4 xr = *(const float4*)&xt[kk*S3 + tr*4];
            float xv[4] = {xr.x, xr.y, xr.z, xr.w};
            float wv[16];
            #pragma unroll
            for (int q = 0; q < 4; ++q){
                float4 w = *(const float4*)&Ws[k*128 + tc*16 + q*4];
                wv[q*4+0]=w.x; wv[q*4+1]=w.y; wv[q*4+2]=w.z; wv[q*4+3]=w.w;
            }
            #pragma unroll
            for (int r = 0; r < 4; ++r)
                #pragma unroll
                for (int c = 0; c < 16; ++c) acc[r][c] += xv[r]*wv[c];
        }
    }
    #pragma unroll
    for (int r = 0; r < 4; ++r){
        int m = m0 + tr*4 + r;
        if (m < M2){
            #pragma unroll
            for (int q = 0; q < 4; ++q){
                float4 o;
                o.x = celu1(acc[r][q*4+0]); o.y = celu1(acc[r][q*4+1]);
                o.z = celu1(acc[r][q*4+2]); o.w = celu1(acc[r][q*4+3]);
                *(float4*)&f2[(size_t)m*128 + tc*16 + q*4] = o;
            }
        }
    }
}

// ================= stage-3 GEMM + block-local segmax, 4 glimpses/block =================
__global__ __launch_bounds__(256) void k_msg3g(const float* __restrict__ f2,
                                               const float* __restrict__ ps2,
                                               const int* __restrict__ seg2,
                                               const float* __restrict__ W3l,
                                               const float* __restrict__ b3l,
                                               float* __restrict__ agg3, int G){
    __shared__ float Wh[131*64];   // 33.5 KB column half
    __shared__ float xt[32*S3];    // 16.9 KB
    __shared__ float shAgg[256];   // [4 glimpses][64 ch]
    const int tid = threadIdx.x;
    const int cb = blockIdx.y * 64;
    const int g0 = blockIdx.x * 4;
    const int S  = seg2[2*g0];
    int n0 = seg2[2*g0+1];
    int nA = (g0+1 < G) ? seg2[2*(g0+1)+1] : 0;
    int nB = (g0+2 < G) ? seg2[2*(g0+2)+1] : 0;
    int nC = (g0+3 < G) ? seg2[2*(g0+3)+1] : 0;
    const int B1 = n0, B2 = B1 + nA, B3 = B2 + nB, T = B3 + nC;
    for (int t = tid; t < 131*64; t += 256){
        int k = t >> 6, c = t & 63;
        Wh[t] = W3l[k*128 + cb + c];
    }
    shAgg[tid] = 0.f;
    const int tr = tid & 31, tc = tid >> 5;
    float bias[8];
    #pragma unroll
    for (int c = 0; c < 8; ++c) bias[c] = b3l[cb + tc*8 + c];

    for (int w0 = 0; w0 < T; w0 += 128){
        float acc[4][8];
        #pragma unroll
        for (int r = 0; r < 4; ++r)
            #pragma unroll
            for (int c = 0; c < 8; ++c) acc[r][c] = bias[c];
        for (int c0 = 0; c0 < 128; c0 += 32){
            __syncthreads();
            for (int t = tid; t < 128*8; t += 256){
                int row = t >> 3, kq = t & 7;
                int ridx = w0 + row;
                float4 v = (ridx < T) ? *(const float4*)&f2[(size_t)(S+ridx)*128 + c0 + kq*4]
                                      : make_float4(0.f,0.f,0.f,0.f);
                xt[(kq*4+0)*S3 + row] = v.x;
                xt[(kq*4+1)*S3 + row] = v.y;
                xt[(kq*4+2)*S3 + row] = v.z;
                xt[(kq*4+3)*S3 + row] = v.w;
            }
            __syncthreads();
            #pragma unroll 8
            for (int kk = 0; kk < 32; ++kk){
                int k = c0 + kk;
                float4 xr = *(const float4*)&xt[kk*S3 + tr*4];
                float xv[4] = {xr.x, xr.y, xr.z, xr.w};
                float4 wa = *(const float4*)&Wh[k*64 + tc*8];
                float4 wb = *(const float4*)&Wh[k*64 + tc*8 + 4];
                float wv[8] = {wa.x,wa.y,wa.z,wa.w, wb.x,wb.y,wb.z,wb.w};
                #pragma unroll
                for (int r = 0; r < 4; ++r)
                    #pragma unroll
                    for (int c = 0; c < 8; ++c) acc[r][c] += xv[r]*wv[c];
            }
        }
        #pragma unroll
        for (int kk = 0; kk < 3; ++kk){
            const float* w = &Wh[(128+kk)*64 + tc*8];
            float wv[8];
            #pragma unroll
            for (int c = 0; c < 8; ++c) wv[c] = w[c];
            #pragma unroll
            for (int r = 0; r < 4; ++r){
                int ridx = w0 + tr*4 + r;
                float x = (ridx < T) ? ps2[(size_t)(S+ridx)*3 + kk] : 0.f;
                #pragma unroll
                for (int c = 0; c < 8; ++c) acc[r][c] += x*wv[c];
            }
        }
        // run-merged segmax (4 consecutive rows span at most 2 glimpses)
        float mx[8];
        int cur = -1;
        #pragma unroll
        for (int r = 0; r < 4; ++r){
            int ridx = w0 + tr*4 + r;
            if (ridx < T){
                int loc = (ridx >= B1) + (ridx >= B2) + (ridx >= B3);
                if (loc != cur){
                    if (cur >= 0){
                        #pragma unroll
                        for (int c = 0; c < 8; ++c)
                            atomicMaxNonneg(&shAgg[cur*64 + tc*8 + c], mx[c]);
                    }
                    cur = loc;
                    #pragma unroll
                    for (int c = 0; c < 8; ++c) mx[c] = fmaxf(acc[r][c], 0.f);
                } else {
                    #pragma unroll
                    for (int c = 0; c < 8; ++c) mx[c] = fmaxf(mx[c], fmaxf(acc[r][c], 0.f));
                }
            }
        }
        if (cur >= 0){
            #pragma unroll
            for (int c = 0; c < 8; ++c)
                atomicMaxNonneg(&shAgg[cur*64 + tc*8 + c], mx[c]);
        }
    }
    __syncthreads();
    {
        int loc = tid >> 6, c = tid & 63;
        int g = g0 + loc;
        if (g < G)
            agg3[(size_t)g*128 + cb + c] = shAgg[loc*64 + c];
    }
}

// ================= head =================
__global__ __launch_bounds__(256) void k_head(const float* __restrict__ agg3,
                                              const float* __restrict__ W3g,
                                              const float* __restrict__ b3g,
                                              const float* __restrict__ Wlin,
                                              const float* __restrict__ blin,
                                              const float* __restrict__ eps,
                                              float* __restrict__ out, int G){
    __shared__ float a3[128];
    __shared__ float f3s[256];
    __shared__ float hs[256];
    int g = blockIdx.x;
    int j = threadIdx.x;
    if (j < 128) a3[j] = agg3[(size_t)g*128 + j];
    __syncthreads();

    float v = b3g[j];
    for (int k = 0; k < 128; ++k) v += a3[k] * W3g[k*256 + j];
    v = celu1(v);
    f3s[j] = v;
    const size_t o_zm = (size_t)64*G, o_mu = (size_t)128*G, o_sg = (size_t)256*G, o_f3 = (size_t)384*G;
    out[o_f3 + (size_t)g*256 + j] = v;
    __syncthreads();

    float h = blin[j];
    for (int k = 0; k < 256; ++k) h += f3s[k] * Wlin[k*256 + j];
    hs[j] = h;
    __syncthreads();

    if (j < 128){
        float mu = hs[j];
        float sg = softplus1(hs[128 + j]);
        float z = mu + sg * eps[(size_t)g*128 + j];
        out[o_mu + (size_t)g*128 + j] = mu;
        out[o_sg + (size_t)g*128 + j] = sg;
        if (j < 64) out[(size_t)g*64 + j] = z;
        else        out[o_zm + (size_t)g*64 + (j - 64)] = z;
    }
}

extern "C" void kernel_launch(void* const* d_in, const int* in_sizes, int n_in,
                              void* d_out, int out_size, void* d_ws, size_t ws_size,
                              hipStream_t stream) {
    const float* rgb  = (const float*)d_in[0];
    const float* pos  = (const float*)d_in[1];
    const float* W1l  = (const float*)d_in[3];
    const float* b1l  = (const float*)d_in[4];
    const float* W1g  = (const float*)d_in[5];
    const float* b1g  = (const float*)d_in[6];
    const float* W2l  = (const float*)d_in[7];
    const float* b2l  = (const float*)d_in[8];
    const float* W2g  = (const float*)d_in[9];
    const float* b2g  = (const float*)d_in[10];
    const float* W3l  = (const float*)d_in[11];
    const float* b3l  = (const float*)d_in[12];
    const float* W3g  = (const float*)d_in[13];
    const float* b3g  = (const float*)d_in[14];
    const float* Wlin = (const float*)d_in[15];
    const float* blin = (const float*)d_in[16];
    const float* eps  = (const float*)d_in[17];
    const int* cl1 = (const int*)d_in[19];
    const int* cl2 = (const int*)d_in[20];

    const int N  = in_sizes[19];
    const int G  = in_sizes[17] / 128;
    const int M1 = in_sizes[20];
    const int M2 = in_sizes[21];
    const int P  = N / G;

    char* ws = (char*)d_ws;
    auto al = [](size_t x){ return (x + 255) & ~(size_t)255; };
    size_t off = 0;
    float* ps1  = (float*)(ws + off); off = al(off + 12ull*M1);
    size_t uni  = ((size_t)64*M1 > (size_t)512*M2) ? (size_t)64*M1 : (size_t)512*M2;
    float* agg1 = (float*)(ws + off);      // agg1 [M1x16] ... later f2 [M2x128] (disjoint lifetimes)
    float* f2   = (float*)(ws + off);
    off = al(off + uni);
    float* cnt1 = (float*)(ws + off); off = al(off + 4ull*M1);
    float* ps2  = (float*)(ws + off); off = al(off + 12ull*M2);
    float* agg2 = (float*)(ws + off); off = al(off + 256ull*M2);
    float* cnt2 = (float*)(ws + off); off = al(off + 4ull*M2);
    float* agg3 = (float*)(ws + off); off = al(off + 512ull*G);
    int*   seg1 = (int*)  (ws + off); off = al(off + 8ull*G);
    int*   seg2 = (int*)  (ws + off); off = al(off + 8ull*G);
    if (off > ws_size) return;

    kA<<<G, 256, 0, stream>>>(rgb, pos, cl1, W1l, b1l, ps1, agg1, cnt1, seg1, P);
    kB<<<G, 256, 0, stream>>>(ps1, agg1, cl2, W1g, b1g, W2l, b2l, seg1, ps2, agg2, cnt2, seg2);
    int gx = (M2 + 127) / 128;
    k_f2f  <<<gx, 256, 0, stream>>>(agg2, W2g, b2g, f2, M2);
    dim3 g3((G + 3) / 4, 2);
    k_msg3g<<<g3, 256, 0, stream>>>(f2, ps2, seg2, W3l, b3l, agg3, G);
    k_head <<<G, 256, 0, stream>>>(agg3, W3g, b3g, Wlin, blin, eps, (float*)d_out, G);
}